// Round 13
// baseline (350.561 us; speedup 1.0000x reference)
//
#include <hip/hip_runtime.h>

typedef float f32x4 __attribute__((ext_vector_type(4)));
typedef _Float16 h16x8 __attribute__((ext_vector_type(8)));
typedef _Float16 h16x4 __attribute__((ext_vector_type(4)));

#define GLOAD_LDS16(gp, lp) __builtin_amdgcn_global_load_lds(               \
    (const __attribute__((address_space(1))) void*)(gp),                    \
    (__attribute__((address_space(3))) void*)(lp), 16, 0, 0)

#define BARX do { __builtin_amdgcn_s_barrier(); asm volatile("" ::: "memory"); } while (0)
#define VMW(N) asm volatile("s_waitcnt vmcnt(" #N ")" ::: "memory")

// ---------------------------------------------------------------------------
// cast x (f32) -> f16, 8 elems/thread
__global__ __launch_bounds__(256) void cast_x(const float* __restrict__ x,
                                              _Float16* __restrict__ xh) {
  long i = (long)blockIdx.x * 256 + threadIdx.x;
  f32x4 a = *(const f32x4*)(x + i * 8);
  f32x4 b = *(const f32x4*)(x + i * 8 + 4);
  h16x8 h;
  h[0] = (_Float16)a[0]; h[1] = (_Float16)a[1];
  h[2] = (_Float16)a[2]; h[3] = (_Float16)a[3];
  h[4] = (_Float16)b[0]; h[5] = (_Float16)b[1];
  h[6] = (_Float16)b[2]; h[7] = (_Float16)b[3];
  *(h16x8*)(xh + i * 8) = h;
}

// ---------------------------------------------------------------------------
// transpose + cast weight: in f32 (K x N) row-major -> out f16 (N x K), *scale
__global__ __launch_bounds__(256) void tcw(const float* __restrict__ in,
                                           _Float16* __restrict__ out,
                                           int Kd, int Nd, float scale) {
  __shared__ float tile[64][65];
  const int t = threadIdx.x;
  const int k0 = blockIdx.y * 64, n0 = blockIdx.x * 64;
  const int tr = t >> 4, tc = (t & 15) * 4;
#pragma unroll
  for (int i = 0; i < 4; ++i) {
    int r = i * 16 + tr;
    f32x4 a = *(const f32x4*)(in + (long)(k0 + r) * Nd + n0 + tc);
    tile[r][tc + 0] = a[0]; tile[r][tc + 1] = a[1];
    tile[r][tc + 2] = a[2]; tile[r][tc + 3] = a[3];
  }
  __syncthreads();
#pragma unroll
  for (int i = 0; i < 4; ++i) {
    int r = i * 16 + tr;
    h16x4 h;
#pragma unroll
    for (int q = 0; q < 4; ++q) h[q] = (_Float16)(tile[tc + q][r] * scale);
    *(h16x4*)(out + (long)(n0 + r) * Kd + k0 + tc) = h;
  }
}

// ---------------------------------------------------------------------------
// f16 tile transpose: in (R x C, ld=Cd) -> out (C x R, ld=R), batched
__global__ __launch_bounds__(256) void trans16(const _Float16* __restrict__ in,
                                               _Float16* __restrict__ out,
                                               int R, int Cd, long ibatch, long obatch) {
  __shared__ _Float16 tile[64][72];
  in += (long)blockIdx.z * ibatch;
  out += (long)blockIdx.z * obatch;
  const int t = threadIdx.x;
  const int r0 = blockIdx.y * 64, c0 = blockIdx.x * 64;
  const int tr = t >> 3, tc8 = (t & 7) * 8;
#pragma unroll
  for (int i = 0; i < 2; ++i) {
    int r = i * 32 + tr;
    h16x8 a = *(const h16x8*)(in + (long)(r0 + r) * Cd + c0 + tc8);
    *(h16x8*)(&tile[r][tc8]) = a;
  }
  __syncthreads();
#pragma unroll
  for (int i = 0; i < 2; ++i) {
    int r = i * 32 + tr;
    h16x8 h;
#pragma unroll
    for (int q = 0; q < 8; ++q) h[q] = tile[tc8 + q][r];
    *(h16x8*)(out + (long)(c0 + r) * R + r0 + tc8) = h;
  }
}

// ---------------------------------------------------------------------------
// lambda_full = exp(sum lq1*lk1) - exp(sum lq2*lk2) + 0.8
__global__ __launch_bounds__(1024) void lambda_k(const float* __restrict__ lq1,
                                                 const float* __restrict__ lk1,
                                                 const float* __restrict__ lq2,
                                                 const float* __restrict__ lk2,
                                                 float* __restrict__ lam) {
  __shared__ float sh1[16], sh2[16];
  const int t = threadIdx.x;
  float p1 = lq1[t] * lk1[t];
  float p2 = lq2[t] * lk2[t];
#pragma unroll
  for (int off = 1; off < 64; off <<= 1) {
    p1 += __shfl_xor(p1, off);
    p2 += __shfl_xor(p2, off);
  }
  if ((t & 63) == 0) { sh1[t >> 6] = p1; sh2[t >> 6] = p2; }
  __syncthreads();
  if (t == 0) {
    float s1 = 0.f, s2 = 0.f;
    for (int i = 0; i < 16; ++i) { s1 += sh1[i]; s2 += sh2[i]; }
    lam[0] = __expf(s1) - __expf(s2) + 0.8f;
  }
}

// ---------------------------------------------------------------------------
// FAT-WAVE GEMM: C(M x N) = A(M x K) @ B(N x K)^T.
// BM=BN=256, BK=32, 4 waves (2x2), per-wave tile 128x128 = 8x8 frags of
// 16x16x32, acc f32x4[8][8] = 256 VGPR -> 1 wave/SIMD (launch_bounds(256,1)).
// Rationale (R12 post-mortem): the 30-33% plateau across 8 schedules is the
// LDS-byte ceiling; FLOP/LDS-byte = Wm*Wn/(Wm+Wn): 64x64=32, 128x64=42.7,
// 128x128=64 (+50%). Latency cover = 2-K-step prefetch lead (ring-of-3,
// counted vmcnt: drain slot S via VMW(8), keep S+1 in flight, stage S+2
// after the barrier; VMW(0) only at the final step) + compiler interleave
// of 16 ds_reads among 64 MFMAs. Proven conflict-free reader/swizzle (R3).
// Requires: M%256==0, N%256==0, K%32==0, K>=96.
template <typename CT>
__global__ __launch_bounds__(256, 1) void gemmt(
    const _Float16* __restrict__ A, const _Float16* __restrict__ B,
    CT* __restrict__ C, int K, int lda, int ldb, int ldc,
    long abatch, long bbatch, long cbatch, long a2, long c2, int natt,
    int nbx, int nby) {
  __shared__ _Float16 As[3][256 * 32];
  __shared__ _Float16 Bs[3][256 * 32];

  // bijective XCD-aware remap (m204); grids are multiples of 8
  const int nwg = gridDim.x;
  const int orig = blockIdx.x;
  const int qd = nwg >> 3, rm = nwg & 7;
  const int xcd = orig & 7, sub = orig >> 3;
  const int wgid = (xcd < rm ? xcd * (qd + 1) : rm * (qd + 1) + (xcd - rm) * qd) + sub;

  const int z = wgid / (nbx * nby);
  const int rem = wgid - z * nbx * nby;
  const int by = rem / nbx;
  const int bx = rem - by * nbx;
  const int att = z % natt;
  const int bz = z / natt;

  const int t = threadIdx.x;
  const int lane = t & 63, wv = t >> 6;
  const int wm = wv >> 1, wn = wv & 1;
  const int lg = lane >> 4, l15 = lane & 15;

  const _Float16* Ab = A + (long)bz * abatch + (long)att * a2 + (long)(by * 256) * lda;
  const _Float16* Bb = B + (long)bz * bbatch + (long)att * a2 + (long)(bx * 256) * ldb;

  // stage K-step S into ring slot `slot`; swizzled global source (R3 layout:
  // LDS slot sp of row r holds global k-slice gs = (sp - (r>>1)) & 3)
  auto stage = [&](int slot, int S) {
    const long ko = (long)S * 32;
#pragma unroll
    for (int j = 0; j < 4; ++j) {
      const int e = t + j * 256;            // chunk 0..1023
      const int r = e >> 2;
      const int gs = ((e & 3) - (r >> 1)) & 3;
      GLOAD_LDS16(Ab + (long)r * lda + ko + gs * 8, &As[slot][e * 8]);
      GLOAD_LDS16(Bb + (long)r * ldb + ko + gs * 8, &Bs[slot][e * 8]);
    }
  };

  // reader offsets (f16 units within a ring slot) — proven 0-conflict shape
  int offA[8], offB[8];
#pragma unroll
  for (int m = 0; m < 8; ++m) {
    const int r = wm * 128 + m * 16 + l15;
    offA[m] = (r * 4 + ((lg + (r >> 1)) & 3)) * 8;
  }
#pragma unroll
  for (int n = 0; n < 8; ++n) {
    const int r = wn * 128 + n * 16 + l15;
    offB[n] = (r * 4 + ((lg + (r >> 1)) & 3)) * 8;
  }

  f32x4 acc[8][8] = {};
  const int NS = K >> 5;

  stage(0, 0); stage(1, 1);
  int cur = 0, nx2 = 2;

  for (int S = 0; S < NS; ++S) {
    // drain slot S's 8 loads; keep slot S+1's 8 in flight (0 only at last)
    if (S == NS - 1) VMW(0);
    else VMW(8);
    BARX;  // slot-S visible; ring slot (S+2)%3 == (S-1)%3 free

    if (S + 2 < NS) stage(nx2, S + 2);

    const _Float16* Ap = &As[cur][0];
    const _Float16* Bp = &Bs[cur][0];
    h16x8 a[8], b[8];
#pragma unroll
    for (int m = 0; m < 8; ++m) a[m] = *(const h16x8*)(Ap + offA[m]);
#pragma unroll
    for (int n = 0; n < 8; ++n) b[n] = *(const h16x8*)(Bp + offB[n]);
#pragma unroll
    for (int m = 0; m < 8; ++m)
#pragma unroll
      for (int n = 0; n < 8; ++n)
        acc[m][n] = __builtin_amdgcn_mfma_f32_16x16x32_f16(a[m], b[n], acc[m][n], 0, 0, 0);

    cur = (cur == 2) ? 0 : cur + 1;
    nx2 = (nx2 == 2) ? 0 : nx2 + 1;
  }

  CT* Cb = C + (long)bz * cbatch + (long)att * c2;
  const int crow0 = by * 256 + wm * 128;
  const int ccol0 = bx * 256 + wn * 128;
#pragma unroll
  for (int m = 0; m < 8; ++m)
#pragma unroll
    for (int n = 0; n < 8; ++n)
#pragma unroll
      for (int j = 0; j < 4; ++j)
        Cb[(long)(crow0 + m * 16 + lg * 4 + j) * ldc + ccol0 + n * 16 + l15] =
            (CT)acc[m][n][j];
}

// ---------------------------------------------------------------------------
// g8 (R12): m201-style 8-phase, kept for PV (NREP=2 -> 256 blocks exact fill)
template <int NREP, typename CT>
__global__ __launch_bounds__(512, 2) void g8(
    const _Float16* __restrict__ A, const _Float16* __restrict__ B,
    CT* __restrict__ C, int K, int lda, int ldb, int ldc,
    long abatch, long bbatch, long cbatch, long a2, long c2, int natt,
    int nbx, int nby) {
  constexpr int BN = NREP * 64;
  constexpr int BNH = BN / 2;
  constexpr int NH = NREP / 2;
  __shared__ _Float16 As[2][2][128 * 64];
  __shared__ _Float16 Bs[2][2][BNH * 64];

  const int nwg = gridDim.x;
  const int orig = blockIdx.x;
  const int qd = nwg >> 3, rm = nwg & 7;
  const int xcd = orig & 7, sub_ = orig >> 3;
  const int wgid = (xcd < rm ? xcd * (qd + 1) : rm * (qd + 1) + (xcd - rm) * qd) + sub_;

  const int z = wgid / (nbx * nby);
  const int rem = wgid - z * nbx * nby;
  const int by = rem / nbx;
  const int bx = rem - by * nbx;
  const int att = z % natt;
  const int bz = z / natt;

  const int t = threadIdx.x;
  const int lane = t & 63, wv = t >> 6;
  const int wm = wv >> 2, wn = wv & 3;
  const int lg = lane >> 4, l15 = lane & 15;

  const _Float16* Ab = A + (long)bz * abatch + (long)att * a2 + (long)(by * 256) * lda;
  const _Float16* Bb = B + (long)bz * bbatch + (long)att * a2 + (long)(bx * BN) * ldb;

  auto stgA = [&](int T, int s) {
    const int db = T & 1;
#pragma unroll
    for (int j = 0; j < 2; ++j) {
      const int c = t + j * 512;
      const int ru = c >> 3, p = c & 7;
      const int gs = p ^ (ru & 7);
      const int grow = (ru < 64) ? (s * 64 + ru) : (128 + s * 64 + (ru - 64));
      GLOAD_LDS16(Ab + (long)grow * lda + T * 64 + gs * 8, &As[db][s][c * 8]);
    }
  };
  auto stgB = [&](int T, int s) {
    const int db = T & 1;
#pragma unroll
    for (int j = 0; j < (NREP == 4 ? 2 : 1); ++j) {
      const int c = t + j * 512;
      const int ru = c >> 3, p = c & 7;
      const int gs = p ^ (ru & 7);
      GLOAD_LDS16(Bb + (long)(s * BNH + ru) * ldb + T * 64 + gs * 8, &Bs[db][s][c * 8]);
    }
  };

  int swz[2];
  swz[0] = ((lg) ^ (l15 & 7)) * 16;
  swz[1] = ((4 + lg) ^ (l15 & 7)) * 16;

  h16x8 fA[4][2], fB0[NH][2], fB1[NH][2];
  f32x4 acc[8][NREP] = {};

  auto rdA = [&](int db, int s) {
    const char* base = (const char*)&As[db][s][0] + (wm * 64 + l15) * 128;
#pragma unroll
    for (int j = 0; j < 4; ++j) {
      fA[j][0] = *(const h16x8*)(base + j * 2048 + swz[0]);
      fA[j][1] = *(const h16x8*)(base + j * 2048 + swz[1]);
    }
  };
  auto rdB = [&](int db, int s, h16x8 (&dst)[NH][2]) {
    const char* base = (const char*)&Bs[db][s][0] + (wn * (BNH / 4) + l15) * 128;
#pragma unroll
    for (int j = 0; j < NH; ++j) {
      dst[j][0] = *(const h16x8*)(base + j * 2048 + swz[0]);
      dst[j][1] = *(const h16x8*)(base + j * 2048 + swz[1]);
    }
  };
  auto QUAD = [&](int ms, int ns, h16x8 (&fb)[NH][2]) {
    __builtin_amdgcn_s_setprio(1);
#pragma unroll
    for (int j = 0; j < 4; ++j)
#pragma unroll
      for (int n = 0; n < NH; ++n) {
        acc[ms * 4 + j][ns * NH + n] = __builtin_amdgcn_mfma_f32_16x16x32_f16(
            fA[j][0], fb[n][0], acc[ms * 4 + j][ns * NH + n], 0, 0, 0);
        acc[ms * 4 + j][ns * NH + n] = __builtin_amdgcn_mfma_f32_16x16x32_f16(
            fA[j][1], fb[n][1], acc[ms * 4 + j][ns * NH + n], 0, 0, 0);
      }
    __builtin_amdgcn_s_setprio(0);
  };

  const int NT = K >> 6;

  stgB(0, 0); stgA(0, 0); stgB(0, 1); stgA(0, 1); stgB(1, 0); stgA(1, 0); stgB(1, 1);
  if constexpr (NREP == 4) VMW(6); else VMW(4);
  BARX;

  for (int T = 0; T + 2 < NT; T += 2) {
    rdA(0, 0); rdB(0, 0, fB0); stgA(T + 1, 1);
    BARX; QUAD(0, 0, fB0); BARX;
    rdB(0, 1, fB1); stgB(T + 2, 0);
    BARX; QUAD(0, 1, fB1); BARX;
    rdA(0, 1); stgA(T + 2, 0);
    BARX; QUAD(1, 1, fB1); BARX;
    stgB(T + 2, 1);
    if constexpr (NREP == 4) VMW(6); else VMW(4);
    BARX; QUAD(1, 0, fB0); BARX;
    rdA(1, 0); rdB(1, 0, fB0); stgA(T + 2, 1);
    BARX; QUAD(0, 0, fB0); BARX;
    rdB(1, 1, fB1); stgB(T + 3, 0);
    BARX; QUAD(0, 1, fB1); BARX;
    rdA(1, 1); stgA(T + 3, 0);
    BARX; QUAD(1, 1, fB1); BARX;
    stgB(T + 3, 1);
    if constexpr (NREP == 4) VMW(6); else VMW(4);
    BARX; QUAD(1, 0, fB0); BARX;
  }

  {
    rdA(0, 0); rdB(0, 0, fB0); stgA(NT - 1, 1);
    BARX; QUAD(0, 0, fB0); BARX;
    rdB(0, 1, fB1);
    BARX; QUAD(0, 1, fB1); BARX;
    rdA(0, 1);
    BARX; QUAD(1, 1, fB1); BARX;
    VMW(0);
    BARX; QUAD(1, 0, fB0); BARX;
    rdA(1, 0); rdB(1, 0, fB0);
    BARX; QUAD(0, 0, fB0); BARX;
    rdB(1, 1, fB1);
    BARX; QUAD(0, 1, fB1); BARX;
    rdA(1, 1);
    BARX; QUAD(1, 1, fB1); BARX;
    QUAD(1, 0, fB0);
  }

  CT* Cb = C + (long)bz * cbatch + (long)att * c2;
  const int crow0 = by * 256 + wm * 128;
  const int ccol0 = bx * BN + wn * (BNH / 4);
#pragma unroll
  for (int ms = 0; ms < 2; ++ms)
#pragma unroll
    for (int j = 0; j < 4; ++j)
#pragma unroll
      for (int ns = 0; ns < 2; ++ns)
#pragma unroll
        for (int n = 0; n < NH; ++n)
#pragma unroll
          for (int q = 0; q < 4; ++q) {
            const int row = crow0 + ms * 64 + j * 16 + lg * 4 + q;
            const int col = ccol0 + ns * BNH + n * 16 + l15;
            Cb[(long)row * ldc + col] = (CT)acc[ms * 4 + j][ns * NH + n][q];
          }
}

// ---------------------------------------------------------------------------
// one wave per row: diff = softmax(S1) - lam * softmax(S2), f16 in/out
__global__ __launch_bounds__(256) void softmax_diff(const _Float16* __restrict__ S1,
                                                    const _Float16* __restrict__ S2,
                                                    _Float16* __restrict__ D,
                                                    const float* __restrict__ lamp) {
  const long row = (long)blockIdx.x * 4 + (threadIdx.x >> 6);
  const int lane = threadIdx.x & 63;
  const float lam = *lamp;
  const _Float16* s1 = S1 + row * 2048;
  const _Float16* s2 = S2 + row * 2048;
  float v1[32], v2[32];
  float m1 = -3e38f, m2 = -3e38f;
#pragma unroll
  for (int j = 0; j < 4; ++j) {
    h16x8 a = ((const h16x8*)s1)[j * 64 + lane];
    h16x8 b = ((const h16x8*)s2)[j * 64 + lane];
#pragma unroll
    for (int q = 0; q < 8; ++q) {
      v1[j * 8 + q] = (float)a[q]; v2[j * 8 + q] = (float)b[q];
      m1 = fmaxf(m1, v1[j * 8 + q]); m2 = fmaxf(m2, v2[j * 8 + q]);
    }
  }
#pragma unroll
  for (int off = 1; off < 64; off <<= 1) {
    m1 = fmaxf(m1, __shfl_xor(m1, off));
    m2 = fmaxf(m2, __shfl_xor(m2, off));
  }
  float l1 = 0.f, l2 = 0.f;
#pragma unroll
  for (int e = 0; e < 32; ++e) {
    v1[e] = __expf(v1[e] - m1); l1 += v1[e];
    v2[e] = __expf(v2[e] - m2); l2 += v2[e];
  }
#pragma unroll
  for (int off = 1; off < 64; off <<= 1) {
    l1 += __shfl_xor(l1, off);
    l2 += __shfl_xor(l2, off);
  }
  const float r1 = 1.f / l1, r2 = lam / l2;
  _Float16* d = D + row * 2048;
#pragma unroll
  for (int j = 0; j < 4; ++j) {
    h16x8 h;
#pragma unroll
    for (int q = 0; q < 8; ++q)
      h[q] = (_Float16)(v1[j * 8 + q] * r1 - v2[j * 8 + q] * r2);
    ((h16x8*)d)[j * 64 + lane] = h;
  }
}

// ---------------------------------------------------------------------------
// one wave per row: out = O / sqrt(mean(O^2) + eps) * 0.2, f16 in, f32 out
__global__ __launch_bounds__(256) void rmsnorm(const _Float16* __restrict__ O,
                                               float* __restrict__ out) {
  const long row = (long)blockIdx.x * 4 + (threadIdx.x >> 6);
  const int lane = threadIdx.x & 63;
  const _Float16* o = O + row * 1024;
  h16x8 a = ((const h16x8*)o)[lane];
  h16x8 b = ((const h16x8*)o)[64 + lane];
  float xa[8], xb[8];
  float ss = 0.f;
#pragma unroll
  for (int q = 0; q < 8; ++q) {
    xa[q] = (float)a[q]; xb[q] = (float)b[q];
    ss += xa[q] * xa[q] + xb[q] * xb[q];
  }
#pragma unroll
  for (int off = 1; off < 64; off <<= 1) ss += __shfl_xor(ss, off);
  const float s = 0.2f * rsqrtf(ss * (1.f / 1024.f) + 1e-5f);
  float* po = out + row * 1024;
  f32x4 r;
#pragma unroll
  for (int q = 0; q < 4; ++q) r[q] = xa[q] * s;
  *(f32x4*)(po + lane * 8) = r;
#pragma unroll
  for (int q = 0; q < 4; ++q) r[q] = xa[4 + q] * s;
  *(f32x4*)(po + lane * 8 + 4) = r;
#pragma unroll
  for (int q = 0; q < 4; ++q) r[q] = xb[q] * s;
  *(f32x4*)(po + 512 + lane * 8) = r;
#pragma unroll
  for (int q = 0; q < 4; ++q) r[q] = xb[4 + q] * s;
  *(f32x4*)(po + 512 + lane * 8 + 4) = r;
}

// ---------------------------------------------------------------------------
extern "C" void kernel_launch(void* const* d_in, const int* in_sizes, int n_in,
                              void* d_out, int out_size, void* d_ws, size_t ws_size,
                              hipStream_t stream) {
  const float* x   = (const float*)d_in[0];
  const float* wq  = (const float*)d_in[1];
  const float* wk  = (const float*)d_in[2];
  const float* wv  = (const float*)d_in[3];
  const float* lq1 = (const float*)d_in[4];
  const float* lk1 = (const float*)d_in[5];
  const float* lq2 = (const float*)d_in[6];
  const float* lk2 = (const float*)d_in[7];
  float* out = (float*)d_out;

  const size_t MB = 1ull << 20;
  char* ws = (char*)d_ws;
  _Float16* xh   = (_Float16*)(ws + 0);          // 16MB  8192x1024
  _Float16* Wp   = (_Float16*)(ws + 16 * MB);    // 10MB  5120x1024 [q|k|v], B^T
  _Float16* qkv  = (_Float16*)(ws + 26 * MB);    // 80MB  8192x5120
  _Float16* vt   = (_Float16*)(ws + 106 * MB);   // 16MB  4 x 1024x2048
  _Float16* S1   = (_Float16*)(ws + 122 * MB);   // 32MB  4 x 2048x2048
  _Float16* S2   = (_Float16*)(ws + 154 * MB);   // 32MB
  float*    lam  = (float*)(ws + 186 * MB);      // 4B
  _Float16* diff = (_Float16*)(ws + 26 * MB);    // 32MB, reuses dead qkv
  _Float16* opre = (_Float16*)(ws + 58 * MB);    // 16MB, reuses dead qkv

  const float scale = 0.17677669529663689f;  // 1024^-0.25

  cast_x<<<4096, 256, 0, stream>>>(x, xh);
  tcw<<<dim3(32, 16), 256, 0, stream>>>(wq, Wp, 1024, 2048, scale);
  tcw<<<dim3(32, 16), 256, 0, stream>>>(wk, Wp + 2048l * 1024, 1024, 2048, 1.0f);
  tcw<<<dim3(16, 16), 256, 0, stream>>>(wv, Wp + 4096l * 1024, 1024, 1024, 1.0f);
  lambda_k<<<1, 1024, 0, stream>>>(lq1, lk1, lq2, lk2, lam);

  // fused projection: qkv = xh @ Wp^T  (8192 x 5120, K=1024); 256x256 tiles
  gemmt<_Float16><<<640, 256, 0, stream>>>(xh, Wp, qkv, 1024, 1024, 1024, 5120,
                                           0, 0, 0, 0, 0, 1, 20, 32);

  // v region (cols 4096..5119) -> vt (b,1024,2048)
  trans16<<<dim3(16, 32, 4), 256, 0, stream>>>(qkv + 4096, vt, 2048, 5120,
                                               2048l * 5120, 1024l * 2048);

  // S1 and S2 fused (natt=2): S_p = q_p @ k_p^T, f16 out; 256x256 tiles
  gemmt<_Float16><<<512, 256, 0, stream>>>(qkv, qkv + 2048, S1, 1024, 5120, 5120, 2048,
                                           2048l * 5120, 2048l * 5120, 2048l * 2048,
                                           1024, 16777216l, 2, 8, 8);

  softmax_diff<<<2048, 256, 0, stream>>>(S1, S2, diff, lam);

  // opre = diff @ vt^T  (K = 2048); 256x128 tiles, 256 blocks exact fill
  g8<2, _Float16><<<256, 512, 0, stream>>>(diff, vt, opre, 2048, 2048, 2048, 1024,
                                           2048l * 2048, 1024l * 2048, 2048l * 1024,
                                           0, 0, 1, 8, 8);

  rmsnorm<<<2048, 256, 0, stream>>>(opre, out);
}

// Round 15
// 271.598 us; speedup vs baseline: 1.2907x; 1.2907x over previous
//
#include <hip/hip_runtime.h>

typedef float f32x4 __attribute__((ext_vector_type(4)));
typedef _Float16 h16x8 __attribute__((ext_vector_type(8)));
typedef _Float16 h16x4 __attribute__((ext_vector_type(4)));

#define GLOAD_LDS16(gp, lp) __builtin_amdgcn_global_load_lds(               \
    (const __attribute__((address_space(1))) void*)(gp),                    \
    (__attribute__((address_space(3))) void*)(lp), 16, 0, 0)

#define BARX do { __builtin_amdgcn_s_barrier(); asm volatile("" ::: "memory"); } while (0)
#define VMW(N) asm volatile("s_waitcnt vmcnt(" #N ")" ::: "memory")

// ---------------------------------------------------------------------------
// cast x (f32) -> f16, 8 elems/thread
__global__ __launch_bounds__(256) void cast_x(const float* __restrict__ x,
                                              _Float16* __restrict__ xh) {
  long i = (long)blockIdx.x * 256 + threadIdx.x;
  f32x4 a = *(const f32x4*)(x + i * 8);
  f32x4 b = *(const f32x4*)(x + i * 8 + 4);
  h16x8 h;
  h[0] = (_Float16)a[0]; h[1] = (_Float16)a[1];
  h[2] = (_Float16)a[2]; h[3] = (_Float16)a[3];
  h[4] = (_Float16)b[0]; h[5] = (_Float16)b[1];
  h[6] = (_Float16)b[2]; h[7] = (_Float16)b[3];
  *(h16x8*)(xh + i * 8) = h;
}

// ---------------------------------------------------------------------------
// transpose + cast weight: in f32 (K x N) row-major -> out f16 (N x K), *scale
__global__ __launch_bounds__(256) void tcw(const float* __restrict__ in,
                                           _Float16* __restrict__ out,
                                           int Kd, int Nd, float scale) {
  __shared__ float tile[64][65];
  const int t = threadIdx.x;
  const int k0 = blockIdx.y * 64, n0 = blockIdx.x * 64;
  const int tr = t >> 4, tc = (t & 15) * 4;
#pragma unroll
  for (int i = 0; i < 4; ++i) {
    int r = i * 16 + tr;
    f32x4 a = *(const f32x4*)(in + (long)(k0 + r) * Nd + n0 + tc);
    tile[r][tc + 0] = a[0]; tile[r][tc + 1] = a[1];
    tile[r][tc + 2] = a[2]; tile[r][tc + 3] = a[3];
  }
  __syncthreads();
#pragma unroll
  for (int i = 0; i < 4; ++i) {
    int r = i * 16 + tr;
    h16x4 h;
#pragma unroll
    for (int q = 0; q < 4; ++q) h[q] = (_Float16)(tile[tc + q][r] * scale);
    *(h16x4*)(out + (long)(n0 + r) * Kd + k0 + tc) = h;
  }
}

// ---------------------------------------------------------------------------
// f16 tile transpose: in (R x C, ld=Cd) -> out (C x R, ld=R), batched
__global__ __launch_bounds__(256) void trans16(const _Float16* __restrict__ in,
                                               _Float16* __restrict__ out,
                                               int R, int Cd, long ibatch, long obatch) {
  __shared__ _Float16 tile[64][72];
  in += (long)blockIdx.z * ibatch;
  out += (long)blockIdx.z * obatch;
  const int t = threadIdx.x;
  const int r0 = blockIdx.y * 64, c0 = blockIdx.x * 64;
  const int tr = t >> 3, tc8 = (t & 7) * 8;
#pragma unroll
  for (int i = 0; i < 2; ++i) {
    int r = i * 32 + tr;
    h16x8 a = *(const h16x8*)(in + (long)(r0 + r) * Cd + c0 + tc8);
    *(h16x8*)(&tile[r][tc8]) = a;
  }
  __syncthreads();
#pragma unroll
  for (int i = 0; i < 2; ++i) {
    int r = i * 32 + tr;
    h16x8 h;
#pragma unroll
    for (int q = 0; q < 8; ++q) h[q] = tile[tc8 + q][r];
    *(h16x8*)(out + (long)(c0 + r) * R + r0 + tc8) = h;
  }
}

// ---------------------------------------------------------------------------
// lambda_full = exp(sum lq1*lk1) - exp(sum lq2*lk2) + 0.8
__global__ __launch_bounds__(1024) void lambda_k(const float* __restrict__ lq1,
                                                 const float* __restrict__ lk1,
                                                 const float* __restrict__ lq2,
                                                 const float* __restrict__ lk2,
                                                 float* __restrict__ lam) {
  __shared__ float sh1[16], sh2[16];
  const int t = threadIdx.x;
  float p1 = lq1[t] * lk1[t];
  float p2 = lq2[t] * lk2[t];
#pragma unroll
  for (int off = 1; off < 64; off <<= 1) {
    p1 += __shfl_xor(p1, off);
    p2 += __shfl_xor(p2, off);
  }
  if ((t & 63) == 0) { sh1[t >> 6] = p1; sh2[t >> 6] = p2; }
  __syncthreads();
  if (t == 0) {
    float s1 = 0.f, s2 = 0.f;
    for (int i = 0; i < 16; ++i) { s1 += sh1[i]; s2 += sh2[i]; }
    lam[0] = __expf(s1) - __expf(s2) + 0.8f;
  }
}

// ---------------------------------------------------------------------------
// C(M x N) = A(M x K) @ B(N x K)^T — m201 8-phase schedule (R12, verified).
// BM=256, BN=NREP*64, BK=64, 2 K-tiles per iteration, 8 waves (2M x 4N),
// per-wave C = 128 x (NREP*16). LDS: As[2dbuf][2msub][128x64],
// Bs[2dbuf][2nsub][(BN/2)x64]. Per K-tile gray walk: (A0,B0) -> (A0,B1) ->
// (A1,B1) -> (A1,B0); each LDS region ds_read ONCE per K-tile (fA reused
// across 2 phases; fB0 held P1->P4, fB1 P2->P3). Reads/phase: 12/4/8/0.
// Stage stream (1 unit/phase): P1:A1(T+1) P2:B0(T+2) P3:A0(T+2) P4:B1(T+2)
// P5:A1(T+2) P6:B0(T+3) P7:A0(T+3) P8:B1(T+3). vmcnt ONLY at P4 & P8:
// VMW(6) NREP=4 / VMW(4) NREP=2 — FIFO ledger verified (2 passing rounds).
// Swizzle: slot p of row r holds global k-slot p^(r&7); reader slot
// (kk*4+lg)^(l15&7). 0 bank conflicts measured (R12).
// Requires: M%256==0, N%BN==0, K%128==0, K>=256.
template <int NREP, typename CT>
__global__ __launch_bounds__(512, 2) void g8(
    const _Float16* __restrict__ A, const _Float16* __restrict__ B,
    CT* __restrict__ C, int K, int lda, int ldb, int ldc,
    long abatch, long bbatch, long cbatch, long a2, long c2, int natt,
    int nbx, int nby) {
  constexpr int BN = NREP * 64;
  constexpr int BNH = BN / 2;       // B rows per sub-unit (128 or 64)
  constexpr int NH = NREP / 2;      // n-frags per sub per wave (2 or 1)
  __shared__ _Float16 As[2][2][128 * 64];
  __shared__ _Float16 Bs[2][2][BNH * 64];

  // bijective XCD-aware remap (m204)
  const int nwg = gridDim.x;
  const int orig = blockIdx.x;
  const int qd = nwg >> 3, rm = nwg & 7;
  const int xcd = orig & 7, sub_ = orig >> 3;
  const int wgid = (xcd < rm ? xcd * (qd + 1) : rm * (qd + 1) + (xcd - rm) * qd) + sub_;

  const int z = wgid / (nbx * nby);
  const int rem = wgid - z * nbx * nby;
  const int by = rem / nbx;
  const int bx = rem - by * nbx;
  const int att = z % natt;
  const int bz = z / natt;

  const int t = threadIdx.x;
  const int lane = t & 63, wv = t >> 6;
  const int wm = wv >> 2, wn = wv & 3;
  const int lg = lane >> 4, l15 = lane & 15;

  const _Float16* Ab = A + (long)bz * abatch + (long)att * a2 + (long)(by * 256) * lda;
  const _Float16* Bb = B + (long)bz * bbatch + (long)att * a2 + (long)(bx * BN) * ldb;

  auto stgA = [&](int T, int s) {   // A-sub s of tile T -> As[T&1][s]
    const int db = T & 1;
#pragma unroll
    for (int j = 0; j < 2; ++j) {
      const int c = t + j * 512;
      const int ru = c >> 3, p = c & 7;
      const int gs = p ^ (ru & 7);
      const int grow = (ru < 64) ? (s * 64 + ru) : (128 + s * 64 + (ru - 64));
      GLOAD_LDS16(Ab + (long)grow * lda + T * 64 + gs * 8, &As[db][s][c * 8]);
    }
  };
  auto stgB = [&](int T, int s) {   // B-sub s of tile T -> Bs[T&1][s]
    const int db = T & 1;
#pragma unroll
    for (int j = 0; j < (NREP == 4 ? 2 : 1); ++j) {
      const int c = t + j * 512;
      const int ru = c >> 3, p = c & 7;
      const int gs = p ^ (ru & 7);
      GLOAD_LDS16(Bb + (long)(s * BNH + ru) * ldb + T * 64 + gs * 8, &Bs[db][s][c * 8]);
    }
  };

  int swz[2];
  swz[0] = ((lg) ^ (l15 & 7)) * 16;
  swz[1] = ((4 + lg) ^ (l15 & 7)) * 16;

  h16x8 fA[4][2], fB0[NH][2], fB1[NH][2];
  f32x4 acc[8][NREP] = {};

  auto rdA = [&](int db, int s) {
    const char* base = (const char*)&As[db][s][0] + (wm * 64 + l15) * 128;
#pragma unroll
    for (int j = 0; j < 4; ++j) {
      fA[j][0] = *(const h16x8*)(base + j * 2048 + swz[0]);
      fA[j][1] = *(const h16x8*)(base + j * 2048 + swz[1]);
    }
  };
  auto rdB = [&](int db, int s, h16x8 (&dst)[NH][2]) {
    const char* base = (const char*)&Bs[db][s][0] + (wn * (BNH / 4) + l15) * 128;
#pragma unroll
    for (int j = 0; j < NH; ++j) {
      dst[j][0] = *(const h16x8*)(base + j * 2048 + swz[0]);
      dst[j][1] = *(const h16x8*)(base + j * 2048 + swz[1]);
    }
  };
  auto QUAD = [&](int ms, int ns, h16x8 (&fb)[NH][2]) {
    __builtin_amdgcn_s_setprio(1);
#pragma unroll
    for (int j = 0; j < 4; ++j)
#pragma unroll
      for (int n = 0; n < NH; ++n) {
        acc[ms * 4 + j][ns * NH + n] = __builtin_amdgcn_mfma_f32_16x16x32_f16(
            fA[j][0], fb[n][0], acc[ms * 4 + j][ns * NH + n], 0, 0, 0);
        acc[ms * 4 + j][ns * NH + n] = __builtin_amdgcn_mfma_f32_16x16x32_f16(
            fA[j][1], fb[n][1], acc[ms * 4 + j][ns * NH + n], 0, 0, 0);
      }
    __builtin_amdgcn_s_setprio(0);
  };

  const int NT = K >> 6;  // even, >= 4

  // prologue: B0(0) A0(0) B1(0) A1(0) B0(1) A0(1) B1(1); force tile0 landed
  stgB(0, 0); stgA(0, 0); stgB(0, 1); stgA(0, 1); stgB(1, 0); stgA(1, 0); stgB(1, 1);
  if constexpr (NREP == 4) VMW(6); else VMW(4);
  BARX;

  for (int T = 0; T + 2 < NT; T += 2) {
    rdA(0, 0); rdB(0, 0, fB0); stgA(T + 1, 1);
    BARX; QUAD(0, 0, fB0); BARX;
    rdB(0, 1, fB1); stgB(T + 2, 0);
    BARX; QUAD(0, 1, fB1); BARX;
    rdA(0, 1); stgA(T + 2, 0);
    BARX; QUAD(1, 1, fB1); BARX;
    stgB(T + 2, 1);
    if constexpr (NREP == 4) VMW(6); else VMW(4);
    BARX; QUAD(1, 0, fB0); BARX;
    rdA(1, 0); rdB(1, 0, fB0); stgA(T + 2, 1);
    BARX; QUAD(0, 0, fB0); BARX;
    rdB(1, 1, fB1); stgB(T + 3, 0);
    BARX; QUAD(0, 1, fB1); BARX;
    rdA(1, 1); stgA(T + 3, 0);
    BARX; QUAD(1, 1, fB1); BARX;
    stgB(T + 3, 1);
    if constexpr (NREP == 4) VMW(6); else VMW(4);
    BARX; QUAD(1, 0, fB0); BARX;
  }

  {  // peeled last iteration: tiles NT-2 (db0), NT-1 (db1)
    rdA(0, 0); rdB(0, 0, fB0); stgA(NT - 1, 1);
    BARX; QUAD(0, 0, fB0); BARX;
    rdB(0, 1, fB1);
    BARX; QUAD(0, 1, fB1); BARX;
    rdA(0, 1);
    BARX; QUAD(1, 1, fB1); BARX;
    VMW(0);
    BARX; QUAD(1, 0, fB0); BARX;
    rdA(1, 0); rdB(1, 0, fB0);
    BARX; QUAD(0, 0, fB0); BARX;
    rdB(1, 1, fB1);
    BARX; QUAD(0, 1, fB1); BARX;
    rdA(1, 1);
    BARX; QUAD(1, 1, fB1); BARX;
    QUAD(1, 0, fB0);
  }

  CT* Cb = C + (long)bz * cbatch + (long)att * c2;
  const int crow0 = by * 256 + wm * 128;
  const int ccol0 = bx * BN + wn * (BNH / 4);
#pragma unroll
  for (int ms = 0; ms < 2; ++ms)
#pragma unroll
    for (int j = 0; j < 4; ++j)
#pragma unroll
      for (int ns = 0; ns < 2; ++ns)
#pragma unroll
        for (int n = 0; n < NH; ++n)
#pragma unroll
          for (int q = 0; q < 4; ++q) {
            const int row = crow0 + ms * 64 + j * 16 + lg * 4 + q;
            const int col = ccol0 + ns * BNH + n * 16 + l15;
            Cb[(long)row * ldc + col] = (CT)acc[ms * 4 + j][ns * NH + n][q];
          }
}

// ---------------------------------------------------------------------------
// one wave per row: diff = softmax(S1) - lam * softmax(S2), f16 in/out
__global__ __launch_bounds__(256) void softmax_diff(const _Float16* __restrict__ S1,
                                                    const _Float16* __restrict__ S2,
                                                    _Float16* __restrict__ D,
                                                    const float* __restrict__ lamp) {
  const long row = (long)blockIdx.x * 4 + (threadIdx.x >> 6);
  const int lane = threadIdx.x & 63;
  const float lam = *lamp;
  const _Float16* s1 = S1 + row * 2048;
  const _Float16* s2 = S2 + row * 2048;
  float v1[32], v2[32];
  float m1 = -3e38f, m2 = -3e38f;
#pragma unroll
  for (int j = 0; j < 4; ++j) {
    h16x8 a = ((const h16x8*)s1)[j * 64 + lane];
    h16x8 b = ((const h16x8*)s2)[j * 64 + lane];
#pragma unroll
    for (int q = 0; q < 8; ++q) {
      v1[j * 8 + q] = (float)a[q]; v2[j * 8 + q] = (float)b[q];
      m1 = fmaxf(m1, v1[j * 8 + q]); m2 = fmaxf(m2, v2[j * 8 + q]);
    }
  }
#pragma unroll
  for (int off = 1; off < 64; off <<= 1) {
    m1 = fmaxf(m1, __shfl_xor(m1, off));
    m2 = fmaxf(m2, __shfl_xor(m2, off));
  }
  float l1 = 0.f, l2 = 0.f;
#pragma unroll
  for (int e = 0; e < 32; ++e) {
    v1[e] = __expf(v1[e] - m1); l1 += v1[e];
    v2[e] = __expf(v2[e] - m2); l2 += v2[e];
  }
#pragma unroll
  for (int off = 1; off < 64; off <<= 1) {
    l1 += __shfl_xor(l1, off);
    l2 += __shfl_xor(l2, off);
  }
  const float r1 = 1.f / l1, r2 = lam / l2;
  _Float16* d = D + row * 2048;
#pragma unroll
  for (int j = 0; j < 4; ++j) {
    h16x8 h;
#pragma unroll
    for (int q = 0; q < 8; ++q)
      h[q] = (_Float16)(v1[j * 8 + q] * r1 - v2[j * 8 + q] * r2);
    ((h16x8*)d)[j * 64 + lane] = h;
  }
}

// ---------------------------------------------------------------------------
// one wave per row: out = O / sqrt(mean(O^2) + eps) * 0.2, f16 in, f32 out
__global__ __launch_bounds__(256) void rmsnorm(const _Float16* __restrict__ O,
                                               float* __restrict__ out) {
  const long row = (long)blockIdx.x * 4 + (threadIdx.x >> 6);
  const int lane = threadIdx.x & 63;
  const _Float16* o = O + row * 1024;
  h16x8 a = ((const h16x8*)o)[lane];
  h16x8 b = ((const h16x8*)o)[64 + lane];
  float xa[8], xb[8];
  float ss = 0.f;
#pragma unroll
  for (int q = 0; q < 8; ++q) {
    xa[q] = (float)a[q]; xb[q] = (float)b[q];
    ss += xa[q] * xa[q] + xb[q] * xb[q];
  }
#pragma unroll
  for (int off = 1; off < 64; off <<= 1) ss += __shfl_xor(ss, off);
  const float s = 0.2f * rsqrtf(ss * (1.f / 1024.f) + 1e-5f);
  float* po = out + row * 1024;
  f32x4 r;
#pragma unroll
  for (int q = 0; q < 4; ++q) r[q] = xa[q] * s;
  *(f32x4*)(po + lane * 8) = r;
#pragma unroll
  for (int q = 0; q < 4; ++q) r[q] = xa[4 + q] * s;
  *(f32x4*)(po + lane * 8 + 4) = r;
#pragma unroll
  for (int q = 0; q < 4; ++q) r[q] = xb[q] * s;
  *(f32x4*)(po + 512 + lane * 8) = r;
#pragma unroll
  for (int q = 0; q < 4; ++q) r[q] = xb[4 + q] * s;
  *(f32x4*)(po + 512 + lane * 8 + 4) = r;
}

// ---------------------------------------------------------------------------
extern "C" void kernel_launch(void* const* d_in, const int* in_sizes, int n_in,
                              void* d_out, int out_size, void* d_ws, size_t ws_size,
                              hipStream_t stream) {
  const float* x   = (const float*)d_in[0];
  const float* wq  = (const float*)d_in[1];
  const float* wk  = (const float*)d_in[2];
  const float* wv  = (const float*)d_in[3];
  const float* lq1 = (const float*)d_in[4];
  const float* lk1 = (const float*)d_in[5];
  const float* lq2 = (const float*)d_in[6];
  const float* lk2 = (const float*)d_in[7];
  float* out = (float*)d_out;

  const size_t MB = 1ull << 20;
  char* ws = (char*)d_ws;
  _Float16* xh   = (_Float16*)(ws + 0);          // 16MB  8192x1024
  _Float16* Wp   = (_Float16*)(ws + 16 * MB);    // 10MB  5120x1024 [q|k|v], B^T
  _Float16* qkv  = (_Float16*)(ws + 26 * MB);    // 80MB  8192x5120
  _Float16* vt   = (_Float16*)(ws + 106 * MB);   // 16MB  4 x 1024x2048
  _Float16* S1   = (_Float16*)(ws + 122 * MB);   // 32MB  4 x 2048x2048
  _Float16* S2   = (_Float16*)(ws + 154 * MB);   // 32MB
  float*    lam  = (float*)(ws + 186 * MB);      // 4B
  _Float16* diff = (_Float16*)(ws + 26 * MB);    // 32MB, reuses dead qkv
  _Float16* opre = (_Float16*)(ws + 58 * MB);    // 16MB, reuses dead qkv

  const float scale = 0.17677669529663689f;  // 1024^-0.25

  cast_x<<<4096, 256, 0, stream>>>(x, xh);
  tcw<<<dim3(32, 16), 256, 0, stream>>>(wq, Wp, 1024, 2048, scale);
  tcw<<<dim3(32, 16), 256, 0, stream>>>(wk, Wp + 2048l * 1024, 1024, 2048, 1.0f);
  tcw<<<dim3(16, 16), 256, 0, stream>>>(wv, Wp + 4096l * 1024, 1024, 1024, 1.0f);
  lambda_k<<<1, 1024, 0, stream>>>(lq1, lk1, lq2, lk2, lam);

  // fused projection: qkv = xh @ Wp^T  (8192 x 5120, K=1024); 256x256 tiles
  g8<4, _Float16><<<640, 512, 0, stream>>>(xh, Wp, qkv, 1024, 1024, 1024, 5120,
                                           0, 0, 0, 0, 0, 1, 20, 32);

  // v region (cols 4096..5119) -> vt (b,1024,2048)
  trans16<<<dim3(16, 32, 4), 256, 0, stream>>>(qkv + 4096, vt, 2048, 5120,
                                               2048l * 5120, 1024l * 2048);

  // S1 and S2 fused (natt=2): S_p = q_p @ k_p^T, f16 out; 256x256 tiles
  g8<4, _Float16><<<512, 512, 0, stream>>>(qkv, qkv + 2048, S1, 1024, 5120, 5120, 2048,
                                           2048l * 5120, 2048l * 5120, 2048l * 2048,
                                           1024, 16777216l, 2, 8, 8);

  softmax_diff<<<2048, 256, 0, stream>>>(S1, S2, diff, lam);

  // opre = diff @ vt^T  (K = 2048); 256x128 tiles, 256 blocks exact fill
  g8<2, _Float16><<<256, 512, 0, stream>>>(diff, vt, opre, 2048, 2048, 2048, 1024,
                                           2048l * 2048, 1024l * 2048, 2048l * 1024,
                                           0, 0, 1, 8, 8);

  rmsnorm<<<2048, 256, 0, stream>>>(opre, out);
}